// Round 13
// baseline (119.537 us; speedup 1.0000x reference)
//
#include <hip/hip_runtime.h>
#include <hip/hip_bf16.h>

typedef __bf16 bf16_t;
typedef bf16_t bf16x2 __attribute__((ext_vector_type(2)));
typedef bf16_t bf16x8 __attribute__((ext_vector_type(8)));
typedef float  floatx4  __attribute__((ext_vector_type(4)));
typedef float  floatx16 __attribute__((ext_vector_type(16)));

constexpr int B = 8, N = 2048, D = 64;

// --- prepass: emit K and V in MFMA fragment order (lane-contiguous 16B frags) ---
// KF[b][kvblk][kd][lane][8]  = K[b][kvblk*32 + (lane&31)][kd*16 + (lane>>5)*8 + j]
// VF[b][kvblk][s2*2+dblk][lane][8] = V[b][kvblk*32 + s2*16 + (lane>>5)*8 + j][dblk*32 + (lane&31)]
__global__ __launch_bounds__(256)
void prepass_kernel(const float* __restrict__ k, const float* __restrict__ v,
                    bf16_t* __restrict__ kf, bf16_t* __restrict__ vf) {
    __shared__ float t[32 * 65];
    const int tid = threadIdx.x;
    const int b   = blockIdx.x & 7;
    const int kvb = blockIdx.x >> 3;                       // 0..63
    const size_t inoff  = ((size_t)b * N + kvb * 32) * D;  // 32x64 fp32 chunk
    const size_t outoff = (size_t)(b * 64 + kvb) * 2048;   // 4x64x8 bf16 frags

    {   // K: coalesced read, fragment-order 16B write
        const float* src = k + inoff;
        floatx4 f0 = *(const floatx4*)(src + tid * 8);
        floatx4 f1 = *(const floatx4*)(src + tid * 8 + 4);
        bf16x8 o;
        #pragma unroll
        for (int j = 0; j < 4; ++j) { o[j] = (bf16_t)f0[j]; o[j + 4] = (bf16_t)f1[j]; }
        const int rr = tid >> 3, kd = (tid >> 1) & 3, hh = tid & 1;
        *(bf16x8*)(kf + outoff + (size_t)kd * 512 + (hh * 32 + rr) * 8) = o;
    }
    {   // V: coalesced read -> padded LDS transpose -> coalesced frag write
        const float* src = v + inoff;
        floatx4 f0 = *(const floatx4*)(src + tid * 8);
        floatx4 f1 = *(const floatx4*)(src + tid * 8 + 4);
        const int rr = tid >> 3, cc = (tid & 7) * 8;
        #pragma unroll
        for (int j = 0; j < 4; ++j) { t[rr * 65 + cc + j] = f0[j]; t[rr * 65 + cc + 4 + j] = f1[j]; }
        __syncthreads();
        const int s2 = tid >> 7, dblk = (tid >> 6) & 1, lane = tid & 63;
        const int hh = lane >> 5, l31 = lane & 31;
        bf16x8 o;
        #pragma unroll
        for (int j = 0; j < 8; ++j)
            o[j] = (bf16_t)t[(s2 * 16 + hh * 8 + j) * 65 + dblk * 32 + l31];
        *(bf16x8*)(vf + outoff + (size_t)(s2 * 2 + dblk) * 512 + lane * 8) = o;
    }
}

// --- flash attention, transposed, fragment-direct, TWO q-tiles per wave (BM=64) ---
// grid 256 = [qt(32)][b(8)], 512 thr = 8 kv-slice waves. No LDS / no barriers in
// the loop. Each K/V fragment load is amortized over 2 q-tiles -> loop traffic
// halves vs R11 (128 MB total). ~190 VGPR -> 2 waves/SIMD (R7 showed 2 vs 4
// waves/SIMD is perf-neutral on this workload). Q pre-scaled by 1/8 (exact).
__global__ __launch_bounds__(512, 2)
void attn_kernel(const float* __restrict__ q, const bf16_t* __restrict__ kf,
                 const bf16_t* __restrict__ vf, float* __restrict__ out) {
    __shared__ char smem[58240];             // o_buf [7][64][32] f32 + l_buf [7][32]
    float* o_buf = (float*)smem;
    float* l_buf = (float*)(smem + 57344);

    const int tid  = threadIdx.x;
    const int lane = tid & 63;
    const int cg   = tid >> 6;     // kv-slice wave: kvblk = it*8 + cg
    const int h    = lane >> 5;
    const int l31  = lane & 31;

    const int b  = blockIdx.x & 7;
    const int q0 = (blockIdx.x >> 3) * 64;

    const bf16_t* kfb = kf + (size_t)b * 131072;
    const bf16_t* vfb = vf + (size_t)b * 131072;

    // Q B-frags for both tiles, pre-scaled by 0.125 (exact pow2) then fp32->bf16
    bf16x8 qf[2][4];
    #pragma unroll
    for (int tqt = 0; tqt < 2; ++tqt) {
        const float* qp = q + ((size_t)b * N + q0 + tqt * 32 + l31) * D + h * 8;
        #pragma unroll
        for (int kd = 0; kd < 4; ++kd) {
            floatx4 f0 = *(const floatx4*)(qp + kd * 16);
            floatx4 f1 = *(const floatx4*)(qp + kd * 16 + 4);
            bf16x8 t;
            #pragma unroll
            for (int j = 0; j < 4; ++j) {
                t[j]     = (bf16_t)(f0[j] * 0.125f);
                t[j + 4] = (bf16_t)(f1[j] * 0.125f);
            }
            qf[tqt][kd] = t;
        }
    }

    floatx16 o_acc[2][2];
    #pragma unroll
    for (int tqt = 0; tqt < 2; ++tqt)
        #pragma unroll
        for (int d = 0; d < 2; ++d)
            #pragma unroll
            for (int i = 0; i < 16; ++i) o_acc[tqt][d][i] = 0.f;
    float l_run[2] = {0.f, 0.f};

    // prefetch kf for it=0 (kvblk = cg)
    bf16x8 kreg[4];
    #pragma unroll
    for (int kd = 0; kd < 4; ++kd)
        kreg[kd] = *(const bf16x8*)(kfb + (size_t)cg * 2048 + kd * 512 + lane * 8);

    #pragma unroll 1
    for (int it = 0; it < 8; ++it) {
        const size_t base = (size_t)(it * 8 + cg) * 2048;

        // vf for THIS iter (shared by both tiles' PV), issued at top
        bf16x8 vreg[4];
        #pragma unroll
        for (int u = 0; u < 4; ++u)
            vreg[u] = *(const bf16x8*)(vfb + base + (size_t)u * 512 + lane * 8);

        // S^T(/8) for both q-tiles (kreg shared)
        floatx16 sa, sb;
        #pragma unroll
        for (int i = 0; i < 16; ++i) { sa[i] = 0.f; sb[i] = 0.f; }
        #pragma unroll
        for (int kd = 0; kd < 4; ++kd) {
            sa = __builtin_amdgcn_mfma_f32_32x32x16_bf16(kreg[kd], qf[0][kd], sa, 0, 0, 0);
            sb = __builtin_amdgcn_mfma_f32_32x32x16_bf16(kreg[kd], qf[1][kd], sb, 0, 0, 0);
        }

        // kf for NEXT iter
        if (it + 1 < 8) {
            const size_t nbase = (size_t)((it + 1) * 8 + cg) * 2048;
            #pragma unroll
            for (int kd = 0; kd < 4; ++kd)
                kreg[kd] = *(const bf16x8*)(kfb + nbase + (size_t)kd * 512 + lane * 8);
        }

        // per q-tile: equality-mask (attn==0 -> weight 0) + exp + pack + PV
        #pragma unroll
        for (int tqt = 0; tqt < 2; ++tqt) {
            const floatx16& s = tqt ? sb : sa;
            int q8[8];
            #pragma unroll
            for (int g = 0; g < 8; ++g) {
                union { int i; bf16x2 h2; } u;
                #pragma unroll
                for (int j = 0; j < 2; ++j) {
                    float x = s[2 * g + j];
                    float p = (x == 0.0f) ? 0.0f : __expf(x);
                    l_run[tqt] += p;
                    u.h2[j] = (bf16_t)p;
                }
                q8[g] = u.i;
            }
            #pragma unroll
            for (int s2 = 0; s2 < 2; ++s2) {
                int r0 = __shfl_xor(q8[4 * s2 + 0], 32);
                int r1 = __shfl_xor(q8[4 * s2 + 1], 32);
                int r2 = __shfl_xor(q8[4 * s2 + 2], 32);
                int r3 = __shfl_xor(q8[4 * s2 + 3], 32);
                union { int i4[4]; bf16x8 v; } bf;
                bf.i4[0] = h ? r2 : q8[4 * s2 + 0];
                bf.i4[1] = h ? r3 : q8[4 * s2 + 1];
                bf.i4[2] = h ? q8[4 * s2 + 2] : r0;
                bf.i4[3] = h ? q8[4 * s2 + 3] : r1;
                #pragma unroll
                for (int dblk = 0; dblk < 2; ++dblk)
                    o_acc[tqt][dblk] = __builtin_amdgcn_mfma_f32_32x32x16_bf16(
                        vreg[s2 * 2 + dblk], bf.v, o_acc[tqt][dblk], 0, 0, 0);
            }
        }
    }

    // complete denoms (partner half-wave holds the other 16 kv rows)
    l_run[0] += __shfl_xor(l_run[0], 32);
    l_run[1] += __shfl_xor(l_run[1], 32);

    // merge the 8 kv-slice partials, one q-tile at a time through shared o_buf
    #pragma unroll 1
    for (int tqt = 0; tqt < 2; ++tqt) {
        if (tqt) __syncthreads();   // previous tile's reads complete before overwrite
        if (cg > 0) {
            float* ob = o_buf + (size_t)(cg - 1) * 2048;
            #pragma unroll
            for (int dblk = 0; dblk < 2; ++dblk)
                #pragma unroll
                for (int i = 0; i < 16; ++i) {
                    const int d = (i & 3) + 8 * (i >> 2) + 4 * h + dblk * 32;
                    ob[d * 32 + l31] = o_acc[tqt][dblk][i];
                }
            if (h == 0) l_buf[(cg - 1) * 32 + l31] = l_run[tqt];
        }
        __syncthreads();
        if (cg == 0) {
            float lsum = l_run[tqt];
            #pragma unroll
            for (int gg = 0; gg < 7; ++gg) lsum += l_buf[gg * 32 + l31];
            const float inv_l = 1.0f / lsum;
            float* op = out + ((size_t)b * N + q0 + tqt * 32 + l31) * D;
            #pragma unroll
            for (int dblk = 0; dblk < 2; ++dblk)
                #pragma unroll
                for (int g = 0; g < 4; ++g) {
                    const int d0 = 8 * g + 4 * h + dblk * 32;
                    floatx4 o4;
                    #pragma unroll
                    for (int j = 0; j < 4; ++j) {
                        float sum = o_acc[tqt][dblk][4 * g + j];
                        #pragma unroll
                        for (int gg = 0; gg < 7; ++gg)
                            sum += o_buf[(size_t)gg * 2048 + (d0 + j) * 32 + l31];
                        o4[j] = sum * inv_l;
                    }
                    *(floatx4*)(op + d0) = o4;
                }
        }
    }
}

extern "C" void kernel_launch(void* const* d_in, const int* in_sizes, int n_in,
                              void* d_out, int out_size, void* d_ws, size_t ws_size,
                              hipStream_t stream) {
    const float* q = (const float*)d_in[0];
    const float* k = (const float*)d_in[1];
    const float* v = (const float*)d_in[2];
    float* out = (float*)d_out;
    bf16_t* kfrag = (bf16_t*)d_ws;                                    // 2 MB
    bf16_t* vfrag = (bf16_t*)((char*)d_ws + (size_t)B * N * D * 2);   // 2 MB

    hipLaunchKernelGGL(prepass_kernel, dim3(512), dim3(256), 0, stream, k, v, kfrag, vfrag);
    hipLaunchKernelGGL(attn_kernel, dim3(256), dim3(512), 0, stream, q, kfrag, vfrag, out);
}

// Round 14
// 83.654 us; speedup vs baseline: 1.4289x; 1.4289x over previous
//
#include <hip/hip_runtime.h>
#include <hip/hip_bf16.h>

typedef __bf16 bf16_t;
typedef bf16_t bf16x2 __attribute__((ext_vector_type(2)));
typedef bf16_t bf16x8 __attribute__((ext_vector_type(8)));
typedef float  floatx4  __attribute__((ext_vector_type(4)));
typedef float  floatx16 __attribute__((ext_vector_type(16)));

constexpr int B = 8, N = 2048, D = 64;

// --- prepass: emit K and V in MFMA fragment order (lane-contiguous 16B frags) ---
// KF[b][kvblk][kd][lane][8]  = K[b][kvblk*32 + (lane&31)][kd*16 + (lane>>5)*8 + j]
// VF[b][kvblk][s2*2+dblk][lane][8] = V[b][kvblk*32 + s2*16 + (lane>>5)*8 + j][dblk*32 + (lane&31)]
__global__ __launch_bounds__(256)
void prepass_kernel(const float* __restrict__ k, const float* __restrict__ v,
                    bf16_t* __restrict__ kf, bf16_t* __restrict__ vf) {
    __shared__ float t[32 * 65];
    const int tid = threadIdx.x;
    const int b   = blockIdx.x & 7;
    const int kvb = blockIdx.x >> 3;                       // 0..63
    const size_t inoff  = ((size_t)b * N + kvb * 32) * D;  // 32x64 fp32 chunk
    const size_t outoff = (size_t)(b * 64 + kvb) * 2048;   // 4x64x8 bf16 frags

    {   // K: coalesced read, fragment-order 16B write
        const float* src = k + inoff;
        floatx4 f0 = *(const floatx4*)(src + tid * 8);
        floatx4 f1 = *(const floatx4*)(src + tid * 8 + 4);
        bf16x8 o;
        #pragma unroll
        for (int j = 0; j < 4; ++j) { o[j] = (bf16_t)f0[j]; o[j + 4] = (bf16_t)f1[j]; }
        const int rr = tid >> 3, kd = (tid >> 1) & 3, hh = tid & 1;
        *(bf16x8*)(kf + outoff + (size_t)kd * 512 + (hh * 32 + rr) * 8) = o;
    }
    {   // V: coalesced read -> padded LDS transpose -> coalesced frag write
        const float* src = v + inoff;
        floatx4 f0 = *(const floatx4*)(src + tid * 8);
        floatx4 f1 = *(const floatx4*)(src + tid * 8 + 4);
        const int rr = tid >> 3, cc = (tid & 7) * 8;
        #pragma unroll
        for (int j = 0; j < 4; ++j) { t[rr * 65 + cc + j] = f0[j]; t[rr * 65 + cc + 4 + j] = f1[j]; }
        __syncthreads();
        const int s2 = tid >> 7, dblk = (tid >> 6) & 1, lane = tid & 63;
        const int hh = lane >> 5, l31 = lane & 31;
        bf16x8 o;
        #pragma unroll
        for (int j = 0; j < 8; ++j)
            o[j] = (bf16_t)t[(s2 * 16 + hh * 8 + j) * 65 + dblk * 32 + l31];
        *(bf16x8*)(vf + outoff + (size_t)(s2 * 2 + dblk) * 512 + lane * 8) = o;
    }
}

// --- flash attention, transposed, fragment-direct, TWO q-tiles per wave (BM=64) ---
// grid 256 = [qt(32)][b(8)], 512 thr = 8 kv-slice waves. No LDS / no barriers in
// the loop; K/V fragment loads amortized over 2 q-tiles (128 MB total traffic).
// ALL o_acc indexing is compile-time static (R13's runtime-indexed epilogue
// demoted o_acc to scratch: VGPR=100, 33 MB spill writes). ~170 VGPR target.
__global__ __launch_bounds__(512, 2)
void attn_kernel(const float* __restrict__ q, const bf16_t* __restrict__ kf,
                 const bf16_t* __restrict__ vf, float* __restrict__ out) {
    __shared__ char smem[58240];             // o_buf [7][64][32] f32 + l_buf [7][32]
    float* o_buf = (float*)smem;
    float* l_buf = (float*)(smem + 57344);

    const int tid  = threadIdx.x;
    const int lane = tid & 63;
    const int cg   = tid >> 6;     // kv-slice wave: kvblk = it*8 + cg
    const int h    = lane >> 5;
    const int l31  = lane & 31;

    const int b  = blockIdx.x & 7;
    const int q0 = (blockIdx.x >> 3) * 64;

    const bf16_t* kfb = kf + (size_t)b * 131072;
    const bf16_t* vfb = vf + (size_t)b * 131072;

    // Q B-frags for both tiles, pre-scaled by 0.125 (exact pow2) then fp32->bf16
    bf16x8 qf[2][4];
    #pragma unroll
    for (int tqt = 0; tqt < 2; ++tqt) {
        const float* qp = q + ((size_t)b * N + q0 + tqt * 32 + l31) * D + h * 8;
        #pragma unroll
        for (int kd = 0; kd < 4; ++kd) {
            floatx4 f0 = *(const floatx4*)(qp + kd * 16);
            floatx4 f1 = *(const floatx4*)(qp + kd * 16 + 4);
            bf16x8 t;
            #pragma unroll
            for (int j = 0; j < 4; ++j) {
                t[j]     = (bf16_t)(f0[j] * 0.125f);
                t[j + 4] = (bf16_t)(f1[j] * 0.125f);
            }
            qf[tqt][kd] = t;
        }
    }

    floatx16 oa0, oa1, ob0, ob1;   // scalars, never runtime-indexed
    #pragma unroll
    for (int i = 0; i < 16; ++i) { oa0[i] = 0.f; oa1[i] = 0.f; ob0[i] = 0.f; ob1[i] = 0.f; }
    float l_a = 0.f, l_b = 0.f;

    // prefetch kf for it=0 (kvblk = cg)
    bf16x8 kreg[4];
    #pragma unroll
    for (int kd = 0; kd < 4; ++kd)
        kreg[kd] = *(const bf16x8*)(kfb + (size_t)cg * 2048 + kd * 512 + lane * 8);

    #pragma unroll 1
    for (int it = 0; it < 8; ++it) {
        const size_t base = (size_t)(it * 8 + cg) * 2048;

        // vf for THIS iter (shared by both tiles' PV), issued at top
        bf16x8 vreg[4];
        #pragma unroll
        for (int u = 0; u < 4; ++u)
            vreg[u] = *(const bf16x8*)(vfb + base + (size_t)u * 512 + lane * 8);

        // S^T(/8) for both q-tiles (kreg shared)
        floatx16 sa, sb;
        #pragma unroll
        for (int i = 0; i < 16; ++i) { sa[i] = 0.f; sb[i] = 0.f; }
        #pragma unroll
        for (int kd = 0; kd < 4; ++kd) {
            sa = __builtin_amdgcn_mfma_f32_32x32x16_bf16(kreg[kd], qf[0][kd], sa, 0, 0, 0);
            sb = __builtin_amdgcn_mfma_f32_32x32x16_bf16(kreg[kd], qf[1][kd], sb, 0, 0, 0);
        }

        // kf for NEXT iter
        if (it + 1 < 8) {
            const size_t nbase = (size_t)((it + 1) * 8 + cg) * 2048;
            #pragma unroll
            for (int kd = 0; kd < 4; ++kd)
                kreg[kd] = *(const bf16x8*)(kfb + nbase + (size_t)kd * 512 + lane * 8);
        }

        // tile A: equality-mask (attn==0 -> weight 0) + exp + pack + PV
        {
            int q8[8];
            #pragma unroll
            for (int g = 0; g < 8; ++g) {
                union { int i; bf16x2 h2; } u;
                #pragma unroll
                for (int j = 0; j < 2; ++j) {
                    float x = sa[2 * g + j];
                    float p = (x == 0.0f) ? 0.0f : __expf(x);
                    l_a += p;
                    u.h2[j] = (bf16_t)p;
                }
                q8[g] = u.i;
            }
            #pragma unroll
            for (int s2 = 0; s2 < 2; ++s2) {
                int r0 = __shfl_xor(q8[4 * s2 + 0], 32);
                int r1 = __shfl_xor(q8[4 * s2 + 1], 32);
                int r2 = __shfl_xor(q8[4 * s2 + 2], 32);
                int r3 = __shfl_xor(q8[4 * s2 + 3], 32);
                union { int i4[4]; bf16x8 v; } bf;
                bf.i4[0] = h ? r2 : q8[4 * s2 + 0];
                bf.i4[1] = h ? r3 : q8[4 * s2 + 1];
                bf.i4[2] = h ? q8[4 * s2 + 2] : r0;
                bf.i4[3] = h ? q8[4 * s2 + 3] : r1;
                oa0 = __builtin_amdgcn_mfma_f32_32x32x16_bf16(vreg[s2 * 2 + 0], bf.v, oa0, 0, 0, 0);
                oa1 = __builtin_amdgcn_mfma_f32_32x32x16_bf16(vreg[s2 * 2 + 1], bf.v, oa1, 0, 0, 0);
            }
        }
        // tile B
        {
            int q8[8];
            #pragma unroll
            for (int g = 0; g < 8; ++g) {
                union { int i; bf16x2 h2; } u;
                #pragma unroll
                for (int j = 0; j < 2; ++j) {
                    float x = sb[2 * g + j];
                    float p = (x == 0.0f) ? 0.0f : __expf(x);
                    l_b += p;
                    u.h2[j] = (bf16_t)p;
                }
                q8[g] = u.i;
            }
            #pragma unroll
            for (int s2 = 0; s2 < 2; ++s2) {
                int r0 = __shfl_xor(q8[4 * s2 + 0], 32);
                int r1 = __shfl_xor(q8[4 * s2 + 1], 32);
                int r2 = __shfl_xor(q8[4 * s2 + 2], 32);
                int r3 = __shfl_xor(q8[4 * s2 + 3], 32);
                union { int i4[4]; bf16x8 v; } bf;
                bf.i4[0] = h ? r2 : q8[4 * s2 + 0];
                bf.i4[1] = h ? r3 : q8[4 * s2 + 1];
                bf.i4[2] = h ? q8[4 * s2 + 2] : r0;
                bf.i4[3] = h ? q8[4 * s2 + 3] : r1;
                ob0 = __builtin_amdgcn_mfma_f32_32x32x16_bf16(vreg[s2 * 2 + 0], bf.v, ob0, 0, 0, 0);
                ob1 = __builtin_amdgcn_mfma_f32_32x32x16_bf16(vreg[s2 * 2 + 1], bf.v, ob1, 0, 0, 0);
            }
        }
    }

    // complete denoms (partner half-wave holds the other 16 kv rows)
    l_a += __shfl_xor(l_a, 32);
    l_b += __shfl_xor(l_b, 32);

    // ---- merge tile A (static indexing throughout) ----
    if (cg > 0) {
        float* ob = o_buf + (size_t)(cg - 1) * 2048;
        #pragma unroll
        for (int i = 0; i < 16; ++i) {
            const int d = (i & 3) + 8 * (i >> 2) + 4 * h;
            ob[d * 32 + l31] = oa0[i];
            ob[(d + 32) * 32 + l31] = oa1[i];
        }
        if (h == 0) l_buf[(cg - 1) * 32 + l31] = l_a;
    }
    __syncthreads();
    if (cg == 0) {
        float lsum = l_a;
        #pragma unroll
        for (int gg = 0; gg < 7; ++gg) lsum += l_buf[gg * 32 + l31];
        const float inv_l = 1.0f / lsum;
        float* op = out + ((size_t)b * N + q0 + l31) * D;
        #pragma unroll
        for (int g = 0; g < 4; ++g) {
            const int d0 = 8 * g + 4 * h;
            floatx4 o4, o5;
            #pragma unroll
            for (int j = 0; j < 4; ++j) {
                float s0 = oa0[4 * g + j], s1 = oa1[4 * g + j];
                #pragma unroll
                for (int gg = 0; gg < 7; ++gg) {
                    s0 += o_buf[(size_t)gg * 2048 + (d0 + j) * 32 + l31];
                    s1 += o_buf[(size_t)gg * 2048 + (d0 + 32 + j) * 32 + l31];
                }
                o4[j] = s0 * inv_l;
                o5[j] = s1 * inv_l;
            }
            *(floatx4*)(op + d0) = o4;
            *(floatx4*)(op + d0 + 32) = o5;
        }
    }
    __syncthreads();   // tile A reads complete before tile B overwrites o_buf

    // ---- merge tile B ----
    if (cg > 0) {
        float* ob = o_buf + (size_t)(cg - 1) * 2048;
        #pragma unroll
        for (int i = 0; i < 16; ++i) {
            const int d = (i & 3) + 8 * (i >> 2) + 4 * h;
            ob[d * 32 + l31] = ob0[i];
            ob[(d + 32) * 32 + l31] = ob1[i];
        }
        if (h == 0) l_buf[(cg - 1) * 32 + l31] = l_b;
    }
    __syncthreads();
    if (cg == 0) {
        float lsum = l_b;
        #pragma unroll
        for (int gg = 0; gg < 7; ++gg) lsum += l_buf[gg * 32 + l31];
        const float inv_l = 1.0f / lsum;
        float* op = out + ((size_t)b * N + q0 + 32 + l31) * D;
        #pragma unroll
        for (int g = 0; g < 4; ++g) {
            const int d0 = 8 * g + 4 * h;
            floatx4 o4, o5;
            #pragma unroll
            for (int j = 0; j < 4; ++j) {
                float s0 = ob0[4 * g + j], s1 = ob1[4 * g + j];
                #pragma unroll
                for (int gg = 0; gg < 7; ++gg) {
                    s0 += o_buf[(size_t)gg * 2048 + (d0 + j) * 32 + l31];
                    s1 += o_buf[(size_t)gg * 2048 + (d0 + 32 + j) * 32 + l31];
                }
                o4[j] = s0 * inv_l;
                o5[j] = s1 * inv_l;
            }
            *(floatx4*)(op + d0) = o4;
            *(floatx4*)(op + d0 + 32) = o5;
        }
    }
}

extern "C" void kernel_launch(void* const* d_in, const int* in_sizes, int n_in,
                              void* d_out, int out_size, void* d_ws, size_t ws_size,
                              hipStream_t stream) {
    const float* q = (const float*)d_in[0];
    const float* k = (const float*)d_in[1];
    const float* v = (const float*)d_in[2];
    float* out = (float*)d_out;
    bf16_t* kfrag = (bf16_t*)d_ws;                                    // 2 MB
    bf16_t* vfrag = (bf16_t*)((char*)d_ws + (size_t)B * N * D * 2);   // 2 MB

    hipLaunchKernelGGL(prepass_kernel, dim3(512), dim3(256), 0, stream, k, v, kfrag, vfrag);
    hipLaunchKernelGGL(attn_kernel, dim3(256), dim3(512), 0, stream, q, kfrag, vfrag, out);
}

// Round 15
// 82.767 us; speedup vs baseline: 1.4443x; 1.0107x over previous
//
#include <hip/hip_runtime.h>
#include <hip/hip_bf16.h>

typedef __bf16 bf16_t;
typedef bf16_t bf16x2 __attribute__((ext_vector_type(2)));
typedef bf16_t bf16x8 __attribute__((ext_vector_type(8)));
typedef float  floatx4  __attribute__((ext_vector_type(4)));
typedef float  floatx16 __attribute__((ext_vector_type(16)));

constexpr int B = 8, N = 2048, D = 64;

// --- prepass: emit K and V in MFMA fragment order so the attention loop's
// loads are lane-contiguous (1KB coalesced per wave-load, no LDS staging).
// KF[b][kvblk][kd][lane][8]  = K[b][kvblk*32 + (lane&31)][kd*16 + (lane>>5)*8 + j]
// VF[b][kvblk][s2*2+dblk][lane][8] = V[b][kvblk*32 + s2*16 + (lane>>5)*8 + j][dblk*32 + (lane&31)]
// grid 512 = [kvblk(64)][b(8)], 256 thr.
__global__ __launch_bounds__(256)
void prepass_kernel(const float* __restrict__ k, const float* __restrict__ v,
                    bf16_t* __restrict__ kf, bf16_t* __restrict__ vf) {
    __shared__ float t[32 * 65];
    const int tid = threadIdx.x;
    const int b   = blockIdx.x & 7;
    const int kvb = blockIdx.x >> 3;                       // 0..63
    const size_t inoff  = ((size_t)b * N + kvb * 32) * D;  // 32x64 fp32 chunk
    const size_t outoff = (size_t)(b * 64 + kvb) * 2048;   // 4x64x8 bf16 frags

    // K: coalesced read, fragment-order 16B write
    {
        const float* src = k + inoff;
        floatx4 f0 = *(const floatx4*)(src + tid * 8);
        floatx4 f1 = *(const floatx4*)(src + tid * 8 + 4);
        bf16x8 o;
        #pragma unroll
        for (int j = 0; j < 4; ++j) { o[j] = (bf16_t)f0[j]; o[j + 4] = (bf16_t)f1[j]; }
        const int rr = tid >> 3, kd = (tid >> 1) & 3, hh = tid & 1;
        *(bf16x8*)(kf + outoff + (size_t)kd * 512 + (hh * 32 + rr) * 8) = o;
    }
    // V: coalesced read -> padded LDS tile -> transposed gather -> coalesced frag write
    {
        const float* src = v + inoff;
        floatx4 f0 = *(const floatx4*)(src + tid * 8);
        floatx4 f1 = *(const floatx4*)(src + tid * 8 + 4);
        const int rr = tid >> 3, cc = (tid & 7) * 8;
        #pragma unroll
        for (int j = 0; j < 4; ++j) { t[rr * 65 + cc + j] = f0[j]; t[rr * 65 + cc + 4 + j] = f1[j]; }
        __syncthreads();
        const int s2 = tid >> 7, dblk = (tid >> 6) & 1, lane = tid & 63;
        const int hh = lane >> 5, l31 = lane & 31;
        bf16x8 o;
        #pragma unroll
        for (int j = 0; j < 8; ++j)
            o[j] = (bf16_t)t[(s2 * 16 + hh * 8 + j) * 65 + dblk * 32 + l31];
        *(bf16x8*)(vf + outoff + (size_t)(s2 * 2 + dblk) * 512 + lane * 8) = o;
    }
}

// --- flash attention, transposed (S^T = K Q^T, O^T = V^T P^T), fragment-direct ---
// grid 512 = [qt(64)][b(8)], 512 thr = 8 kv-slice waves. NO LDS / NO barriers in
// the loop. Q pre-scaled by 1/8 (exact pow2 -> S comes out as S/8 bitwise; the
// ==0 equality-mask semantics are unchanged). unroll 2 lets the compiler
// software-pipeline two iteration bodies (exp of i overlaps loads/MFMA of i+1).
__global__ __launch_bounds__(512, 4)
void attn_kernel(const float* __restrict__ q, const bf16_t* __restrict__ kf,
                 const bf16_t* __restrict__ vf, float* __restrict__ out) {
    __shared__ char smem[58240];             // o_buf [7][64][32] f32 + l_buf [7][32]
    float* o_buf = (float*)smem;
    float* l_buf = (float*)(smem + 57344);

    const int tid  = threadIdx.x;
    const int lane = tid & 63;
    const int cg   = tid >> 6;     // kv-slice wave: handles kvblk = it*8 + cg
    const int h    = lane >> 5;
    const int l31  = lane & 31;

    const int b  = blockIdx.x & 7;
    const int q0 = (blockIdx.x >> 3) * 32;

    const bf16_t* kfb = kf + (size_t)b * 131072;
    const bf16_t* vfb = vf + (size_t)b * 131072;

    // Q B-frags, pre-scaled by 0.125 then fp32->bf16 (exponent shift: exact)
    bf16x8 qf[4];
    {
        const float* qp = q + ((size_t)b * N + q0 + l31) * D + h * 8;
        #pragma unroll
        for (int kd = 0; kd < 4; ++kd) {
            floatx4 f0 = *(const floatx4*)(qp + kd * 16);
            floatx4 f1 = *(const floatx4*)(qp + kd * 16 + 4);
            bf16x8 t;
            #pragma unroll
            for (int j = 0; j < 4; ++j) {
                t[j]     = (bf16_t)(f0[j] * 0.125f);
                t[j + 4] = (bf16_t)(f1[j] * 0.125f);
            }
            qf[kd] = t;
        }
    }

    floatx16 o_acc[2];
    #pragma unroll
    for (int d = 0; d < 2; ++d)
        #pragma unroll
        for (int i = 0; i < 16; ++i) o_acc[d][i] = 0.f;
    float l_run = 0.f;

    // prefetch kf for it=0 (kvblk = cg)
    bf16x8 kreg[4];
    #pragma unroll
    for (int kd = 0; kd < 4; ++kd)
        kreg[kd] = *(const bf16x8*)(kfb + (size_t)cg * 2048 + kd * 512 + lane * 8);

    #pragma unroll 2
    for (int it = 0; it < 8; ++it) {
        const size_t base = (size_t)(it * 8 + cg) * 2048;

        // vf for THIS iter: issued now, consumed after QK+softmax
        bf16x8 vreg[4];
        #pragma unroll
        for (int u = 0; u < 4; ++u)
            vreg[u] = *(const bf16x8*)(vfb + base + (size_t)u * 512 + lane * 8);

        // S^T(/8) = K (Q/8)^T (32kv x 32q)
        floatx16 s;
        #pragma unroll
        for (int i = 0; i < 16; ++i) s[i] = 0.f;
        #pragma unroll
        for (int kd = 0; kd < 4; ++kd)
            s = __builtin_amdgcn_mfma_f32_32x32x16_bf16(kreg[kd], qf[kd], s, 0, 0, 0);

        // kf for NEXT iter (SSA rename handles the WAR with the MFMAs above)
        if (it + 1 < 8) {
            const size_t nbase = (size_t)((it + 1) * 8 + cg) * 2048;
            #pragma unroll
            for (int kd = 0; kd < 4; ++kd)
                kreg[kd] = *(const bf16x8*)(kfb + nbase + (size_t)kd * 512 + lane * 8);
        }

        // equality-mask (attn==0 -> -inf -> weight 0) + exp; pack bf16 pairs
        int q8[8];
        #pragma unroll
        for (int g = 0; g < 8; ++g) {
            union { int i; bf16x2 h2; } u;
            #pragma unroll
            for (int j = 0; j < 2; ++j) {
                float x = s[2 * g + j];
                float p = (x == 0.0f) ? 0.0f : __expf(x);
                l_run += p;
                u.h2[j] = (bf16_t)p;
            }
            q8[g] = u.i;
        }

        // O^T += V^T P^T : A = V-frag (global), B = P^T-frag via half-wave exchange
        #pragma unroll
        for (int s2 = 0; s2 < 2; ++s2) {
            int r0 = __shfl_xor(q8[4 * s2 + 0], 32);
            int r1 = __shfl_xor(q8[4 * s2 + 1], 32);
            int r2 = __shfl_xor(q8[4 * s2 + 2], 32);
            int r3 = __shfl_xor(q8[4 * s2 + 3], 32);
            union { int i4[4]; bf16x8 v; } bf;
            bf.i4[0] = h ? r2 : q8[4 * s2 + 0];
            bf.i4[1] = h ? r3 : q8[4 * s2 + 1];
            bf.i4[2] = h ? q8[4 * s2 + 2] : r0;
            bf.i4[3] = h ? q8[4 * s2 + 3] : r1;
            #pragma unroll
            for (int dblk = 0; dblk < 2; ++dblk)
                o_acc[dblk] = __builtin_amdgcn_mfma_f32_32x32x16_bf16(vreg[s2 * 2 + dblk], bf.v,
                                                                      o_acc[dblk], 0, 0, 0);
        }
    }

    // complete this lane's denom (partner half-wave holds the other 16 kv rows)
    l_run += __shfl_xor(l_run, 32);

    // merge the 8 kv-slice partials (plain sums; epilogue-only LDS use)
    if (cg > 0) {
        float* ob = o_buf + (size_t)(cg - 1) * 2048;
        #pragma unroll
        for (int dblk = 0; dblk < 2; ++dblk)
            #pragma unroll
            for (int i = 0; i < 16; ++i) {
                const int d = (i & 3) + 8 * (i >> 2) + 4 * h + dblk * 32;
                ob[d * 32 + l31] = o_acc[dblk][i];
            }
        if (h == 0) l_buf[(cg - 1) * 32 + l31] = l_run;
    }
    __syncthreads();
    if (cg == 0) {
        float lsum = l_run;
        #pragma unroll
        for (int gg = 0; gg < 7; ++gg) lsum += l_buf[gg * 32 + l31];
        const float inv_l = 1.0f / lsum;
        float* op = out + ((size_t)b * N + q0 + l31) * D;
        #pragma unroll
        for (int dblk = 0; dblk < 2; ++dblk)
            #pragma unroll
            for (int g = 0; g < 4; ++g) {
                const int d0 = 8 * g + 4 * h + dblk * 32;
                floatx4 o4;
                #pragma unroll
                for (int j = 0; j < 4; ++j) {
                    float sum = o_acc[dblk][4 * g + j];
                    #pragma unroll
                    for (int gg = 0; gg < 7; ++gg)
                        sum += o_buf[(size_t)gg * 2048 + (d0 + j) * 32 + l31];
                    o4[j] = sum * inv_l;
                }
                *(floatx4*)(op + d0) = o4;
            }
    }
}

extern "C" void kernel_launch(void* const* d_in, const int* in_sizes, int n_in,
                              void* d_out, int out_size, void* d_ws, size_t ws_size,
                              hipStream_t stream) {
    const float* q = (const float*)d_in[0];
    const float* k = (const float*)d_in[1];
    const float* v = (const float*)d_in[2];
    float* out = (float*)d_out;
    bf16_t* kfrag = (bf16_t*)d_ws;                                    // 2 MB
    bf16_t* vfrag = (bf16_t*)((char*)d_ws + (size_t)B * N * D * 2);   // 2 MB

    hipLaunchKernelGGL(prepass_kernel, dim3(512), dim3(256), 0, stream, k, v, kfrag, vfrag);
    hipLaunchKernelGGL(attn_kernel, dim3(512), dim3(512), 0, stream, q, kfrag, vfrag, out);
}